// Round 12
// baseline (89.231 us; speedup 1.0000x reference)
//
#include <hip/hip_runtime.h>
#include <hip/hip_bf16.h>

#define BB 8
#define NN 512
#define DINC 128
#define DOUTC 128
#define HHC 8
#define EEC 16
#define DHC 16
#define NPROJ 256          // proj blocks at the front of the merged grid

typedef _Float16 h4 __attribute__((ext_vector_type(4)));
typedef float f32x4 __attribute__((ext_vector_type(4)));

__device__ __forceinline__ float wsum(float v){
#pragma unroll
  for (int o=1;o<64;o<<=1) v += __shfl_xor(v,o);
  return v;
}

// =================== merged proj ∥ edge kernel ===================
// Shared static LDS carve-out (max of the two paths = 21760B).
// proj: xln@0 (4352) | xps@4352 (4352) | qs@8704 (13056)
// edge: ef@0 (12288) | stage@12288 (8320) | idx16@20608 (1024) | msk@21632 (64) | cntS@21696

__device__ __forceinline__ void proj_body(
    char* smem, int blk,
    const float* __restrict__ x,
    const float* __restrict__ g1, const float* __restrict__ b1,
    const float* __restrict__ Wp, const float* __restrict__ bp,
    const float* __restrict__ Wq, const float* __restrict__ Wk, const float* __restrict__ Wv,
    _Float16* __restrict__ xph, _Float16* __restrict__ Qh, _Float16* __restrict__ Kh, _Float16* __restrict__ Vh)
{
  _Float16 (*xln)[136] = (_Float16(*)[136])(smem);
  _Float16 (*xps)[136] = (_Float16(*)[136])(smem + 4352);
  _Float16* qs         = (_Float16*)(smem + 8704);     // [3][16][136]
  int tid=threadIdx.x, w=tid>>6, lane=tid&63;
  int c=lane&15, g=lane>>4;
  int row0 = blk*16;
  int b = row0>>9, n0 = row0&(NN-1);

  float ga=g1[lane], gb=g1[lane+64], ba=b1[lane], bbx=b1[lane+64];
#pragma unroll
  for (int rr=0;rr<4;++rr){
    int r = w + rr*4;
    size_t gi = (size_t)(row0+r)*DINC + lane;
    float a = x[gi], cc = x[gi+64];
    float s = wsum(a+cc);
    float q = wsum(a*a+cc*cc);
    float mean = s*(1.f/DINC);
    float var  = q*(1.f/DINC)-mean*mean;
    float rstd = rsqrtf(var+1e-5f);
    xln[r][lane]    = (_Float16)((a -mean)*rstd*ga + ba);
    xln[r][lane+64] = (_Float16)((cc-mean)*rstd*gb + bbx);
  }
  __syncthreads();

#pragma unroll
  for (int oo=0;oo<2;++oo){
    int ot = 2*w+oo;
    float4 bi = *(const float4*)(bp + 16*ot + 4*g);
    f32x4 D; D[0]=bi.x; D[1]=bi.y; D[2]=bi.z; D[3]=bi.w;
#pragma unroll
    for (int kt=0;kt<8;++kt){
      h4 f;
#pragma unroll
      for (int j=0;j<4;++j)
        f[j] = (_Float16)Wp[(size_t)(16*kt+4*g+j)*DOUTC + 16*ot + c];
      h4 hb = *(const h4*)&xln[c][16*kt+4*g];
      D = __builtin_amdgcn_mfma_f32_16x16x16f16(f, hb, D, 0,0,0);
    }
#pragma unroll
    for (int r=0;r<4;++r)
      xps[c][16*ot+4*g+r] = (_Float16)D[r];
  }
  __syncthreads();

#pragma unroll
  for (int pp=0;pp<6;++pp){
    int p = w + pp*4;
    int mat = p>>3, ot = p&7;
    const float* W = (mat==0)? Wq : ((mat==1)? Wk : Wv);
    f32x4 D = {0.f,0.f,0.f,0.f};
#pragma unroll
    for (int kt=0;kt<8;++kt){
      h4 f;
#pragma unroll
      for (int j=0;j<4;++j)
        f[j] = (_Float16)W[(size_t)(16*kt+4*g+j)*DOUTC + 16*ot + c];
      h4 hb = *(const h4*)&xps[c][16*kt+4*g];
      D = __builtin_amdgcn_mfma_f32_16x16x16f16(f, hb, D, 0,0,0);
    }
#pragma unroll
    for (int r=0;r<4;++r)
      qs[(mat*16 + c)*136 + 16*ot+4*g+r] = (_Float16)D[r];
  }
  __syncthreads();

  { // xp (f16) writeout
    int r = tid>>4, seg = tid&15;
    *(float4*)(xph + (size_t)(row0+r)*DOUTC + seg*8) = *(const float4*)&xps[r][seg*8];
  }
#pragma unroll
  for (int mat=0;mat<3;++mat){
    int r = tid>>4, seg = tid&15;
    int h = seg>>1, d = (seg&1)*8;
    _Float16* O = (mat==0)? Qh : ((mat==1)? Kh : Vh);
    *(float4*)(O + (((size_t)b*HHC+h)*NN + n0+r)*DHC + d) = *(const float4*)&qs[(mat*16+r)*136 + seg*8];
  }
}

__device__ __forceinline__ void edge_body(
    char* smem, int bn,
    const float* __restrict__ ea, const int* __restrict__ adj,
    const float* __restrict__ eg, const float* __restrict__ ebi,
    const float* __restrict__ We1, const float* __restrict__ be1,
    const float* __restrict__ We2, const float* __restrict__ be2,
    _Float16* __restrict__ ebias)
{
  _Float16* ef              = (_Float16*)(smem);            // [4*64][24]
  _Float16 (*stage)[520]    = (_Float16(*)[520])(smem + 12288);
  unsigned short* idx16     = (unsigned short*)(smem + 20608);
  unsigned long long* msk   = (unsigned long long*)(smem + 21632);
  int* cntS                 = (int*)(smem + 21696);

  int tid = threadIdx.x, w = tid>>6, lane = tid&63;
  int c = lane&15, g = lane>>4;
  int b = bn >> 9, n = bn & (NN-1);

  const int* adjRow = adj + (size_t)bn*NN;
  int col1 = tid, col2 = tid + 256;
  int v1 = (adjRow[col1] != 0) || (col1 == n);
  int v2 = (adjRow[col2] != 0) || (col2 == n);
  unsigned long long b1m = __ballot(v1);
  unsigned long long b2m = __ballot(v2);
  if (lane==0){ msk[w] = b1m; msk[4+w] = b2m; }

  // MLP weight A-fragments (transposed-layer trick, R3+-verified)
  h4 w1a,w1b,w2a,w2b;
#pragma unroll
  for (int j=0;j<4;++j){
    w1a[j] = (_Float16)We1[(4*g+j)*32 + c];
    w1b[j] = (_Float16)We1[(4*g+j)*32 + 16 + c];
    w2a[j] = (_Float16)((c<8)? We2[(4*g+j)*HHC + c] : 0.f);
    w2b[j] = (_Float16)((c<8)? We2[(16+4*g+j)*HHC + c] : 0.f);
  }
  float4 b2r = *(const float4*)(be2 + (g&1)*4);
  float4 b1a = *(const float4*)(be1 + 4*g);
  float4 b1b = *(const float4*)(be1 + 16 + 4*g);

  __syncthreads();

  int offs[8]; int cnt = 0;
#pragma unroll
  for (int k=0;k<8;++k){ offs[k] = cnt; cnt += __popcll(msk[k]); }
  if (tid==0) *cntS = cnt;

  { // prefill stage with -30000
    _Float16 neg = (_Float16)(-30000.f);
    h4 negv; negv[0]=neg; negv[1]=neg; negv[2]=neg; negv[3]=neg;
#pragma unroll
    for (int i=tid;i<1024;i+=256){
      int h = i>>7, m4 = i&127;
      *(h4*)&stage[h][m4*4] = negv;
    }
  }

  if (v1){
    int pos = offs[w]   + __popcll(msk[w]   & ((1ull<<lane)-1ull));
    idx16[pos] = (unsigned short)col1;
  }
  if (v2){
    int pos = offs[4+w] + __popcll(msk[4+w] & ((1ull<<lane)-1ull));
    idx16[pos] = (unsigned short)col2;
  }
  __syncthreads();

  cnt = *cntS;
  int ng = (cnt + 63) >> 6;
  const float* eaRow = ea + (size_t)bn*NN*EEC;

  for (int grp = w; grp < ng; grp += 4){
    // ---- each lane owns ONE edge: 64B load, in-lane LN (no shfls)
    int slot = grp*64 + lane;
    int sidx = slot < cnt ? slot : cnt-1;
    int idx  = idx16[sidx];
    const float4* ep = (const float4*)(eaRow + (size_t)idx*EEC);
    float4 a0=ep[0], a1=ep[1], a2=ep[2], a3=ep[3];
    float e[16] = {a0.x,a0.y,a0.z,a0.w, a1.x,a1.y,a1.z,a1.w,
                   a2.x,a2.y,a2.z,a2.w, a3.x,a3.y,a3.z,a3.w};
    float s=0.f, q=0.f;
#pragma unroll
    for (int k=0;k<16;++k){ s+=e[k]; q+=e[k]*e[k]; }
    float mean = s*(1.f/EEC);
    float var  = q*(1.f/EEC) - mean*mean;
    float rstd = rsqrtf(var + 1e-5f);
    _Float16 ef16[16];
#pragma unroll
    for (int k=0;k<16;++k)
      ef16[k] = (_Float16)((e[k]-mean)*rstd*eg[k] + ebi[k]);   // eg/ebi: scalar loads
    _Float16* dst = ef + (size_t)(w*64 + lane)*24;
    *(float4*)(dst)     = *(const float4*)&ef16[0];
    *(float4*)(dst + 8) = *(const float4*)&ef16[8];

    // ---- 4 independent 16-edge MFMA sub-tiles
#pragma unroll
    for (int tt=0;tt<4;++tt){
      h4 efr = *(const h4*)(ef + (size_t)(w*64 + tt*16 + c)*24 + 4*g);
      f32x4 d1a = {b1a.x,b1a.y,b1a.z,b1a.w};
      f32x4 d1b = {b1b.x,b1b.y,b1b.z,b1b.w};
      d1a = __builtin_amdgcn_mfma_f32_16x16x16f16(w1a, efr, d1a, 0,0,0);
      d1b = __builtin_amdgcn_mfma_f32_16x16x16f16(w1b, efr, d1b, 0,0,0);
      h4 hfa,hfb;
#pragma unroll
      for (int r=0;r<4;++r){
        hfa[r]=(_Float16)fmaxf(d1a[r],0.f);
        hfb[r]=(_Float16)fmaxf(d1b[r],0.f);
      }
      f32x4 d2 = {0.f,0.f,0.f,0.f};
      d2 = __builtin_amdgcn_mfma_f32_16x16x16f16(w2a, hfa, d2, 0,0,0);
      d2 = __builtin_amdgcn_mfma_f32_16x16x16f16(w2b, hfb, d2, 0,0,0);
      int slot2 = grp*64 + tt*16 + c;
      if (g<2 && slot2<cnt){
        int sidx2 = idx16[slot2];
#pragma unroll
        for (int r=0;r<4;++r){
          float y = d2[r] + ((const float*)&b2r)[r];
          y = fminf(fmaxf(2.f*y,-30.f),30.f);
          float ex = __expf(y);
          float t2 = (ex-1.f)/(ex+1.f);            // tanh
          stage[4*g+r][sidx2] = (_Float16)(5.f*t2);
        }
      }
    }
  }
  __syncthreads();

  size_t base = ((size_t)b*HHC)*NN*NN + (size_t)n*NN;
#pragma unroll
  for (int i=tid;i<512;i+=256){
    int h = i>>6, m8 = i&63;
    *(float4*)(ebias + base + (size_t)h*NN*NN + m8*8) =
        *(const float4*)&stage[h][m8*8];
  }
}

__global__ __launch_bounds__(256) void k_projedge(
    const float* __restrict__ x,
    const float* __restrict__ g1, const float* __restrict__ b1,
    const float* __restrict__ Wp, const float* __restrict__ bp,
    const float* __restrict__ Wq, const float* __restrict__ Wk, const float* __restrict__ Wv,
    _Float16* __restrict__ xph, _Float16* __restrict__ Qh, _Float16* __restrict__ Kh, _Float16* __restrict__ Vh,
    const float* __restrict__ ea, const int* __restrict__ adj,
    const float* __restrict__ eg, const float* __restrict__ ebi,
    const float* __restrict__ We1, const float* __restrict__ be1,
    const float* __restrict__ We2, const float* __restrict__ be2,
    _Float16* __restrict__ ebias)
{
  __shared__ __align__(16) char smem[21760];
  int blk = blockIdx.x;
  if (blk < NPROJ)
    proj_body(smem, blk, x, g1, b1, Wp, bp, Wq, Wk, Wv, xph, Qh, Kh, Vh);
  else
    edge_body(smem, blk - NPROJ, ea, adj, eg, ebi, We1, be1, We2, be2, ebias);
}

// ---------- MFMA attention (R9/R10-verified, unchanged) ----------
__global__ __launch_bounds__(256) void k_attn(
  const _Float16* __restrict__ Qh, const _Float16* __restrict__ Kh, const _Float16* __restrict__ Vh,
  const _Float16* __restrict__ eb, float* __restrict__ ctxb)
{
  __shared__ _Float16 Klds[NN*DHC];
  __shared__ _Float16 Vt[DHC*520];
  int tid = threadIdx.x;
  int bh   = blockIdx.x >> 3;
  int tile = blockIdx.x & 7;
  const _Float16* Kg = Kh + (size_t)bh*NN*DHC;
  const _Float16* Vg = Vh + (size_t)bh*NN*DHC;
  {
    const float4* src = (const float4*)Kg;
    float4* dst = (float4*)Klds;
#pragma unroll
    for (int i=tid;i<1024;i+=256) dst[i]=src[i];
  }
  {
#pragma unroll
    for (int i=tid;i<1024;i+=256){
      int m = i>>1, hf = i&1;
      float4 v4 = *(const float4*)(Vg + (size_t)m*DHC + hf*8);
      const _Float16* hh = (const _Float16*)&v4;
#pragma unroll
      for (int jj=0;jj<8;++jj) Vt[(hf*8+jj)*520 + m] = hh[jj];
    }
  }
  __syncthreads();

  int w = tid>>6, lane = tid&63;
  int c = lane&15, g = lane>>4;
  int n0 = tile*64 + w*16;

  h4 qf = *(const h4*)(Qh + ((size_t)bh*NN + n0 + c)*DHC + 4*g);
  const _Float16* ebw = eb + ((size_t)bh*NN + n0 + c)*NN + 4*g;

  f32x4 zero = {0.f,0.f,0.f,0.f};
  f32x4 acc = zero;
  float rowsum = 0.f;
#pragma unroll
  for (int t=0;t<32;++t){
    h4 kf = *(const h4*)(Klds + (16*t + c)*DHC + 4*g);
    f32x4 d = __builtin_amdgcn_mfma_f32_16x16x16f16(kf, qf, zero, 0, 0, 0);
    h4 e4 = *(const h4*)(ebw + 16*t);
    h4 pa;
#pragma unroll
    for (int r=0;r<4;++r){
      float sv = d[r]*0.25f + (float)e4[r];
      sv = fmaxf(sv,0.f) + 0.2f*fminf(sv,0.f);
      float p = __expf(sv - 6.f);
      rowsum += p;
      pa[r] = (_Float16)p;
    }
    h4 vf = *(const h4*)(Vt + c*520 + 16*t + 4*g);
    acc = __builtin_amdgcn_mfma_f32_16x16x16f16(pa, vf, acc, 0, 0, 0);
  }
  rowsum += __shfl_xor(rowsum,16);
  rowsum += __shfl_xor(rowsum,32);

  int b = bh>>3, h = bh&7;
#pragma unroll
  for (int r=0;r<4;++r){
    float sr = __shfl(rowsum, g*16 + 4*g + r);
    ctxb[((size_t)b*NN + n0 + 4*g + r)*DOUTC + h*DHC + c] = acc[r]/sr;
  }
}

// ---------- FFN v4 (R11-verified) — xp now f16 ----------
__global__ __launch_bounds__(256) void k_ffn(
  const _Float16* __restrict__ xph, const float* __restrict__ ctxb,
  const float* __restrict__ g2, const float* __restrict__ b2v,
  const float* __restrict__ W1, const float* __restrict__ bb1,
  const float* __restrict__ W2, const float* __restrict__ bb2,
  float* __restrict__ out)
{
  __shared__ float    hrow[8][DOUTC];
  __shared__ _Float16 hn[16][136];
  __shared__ float    part[4][8][16][16];

  int tid = threadIdx.x, w = tid>>6, lane = tid&63;
  int c = lane&15, g = lane>>4;
  int n0 = blockIdx.x * 8;

#pragma unroll
  for (int i=tid;i<272;i+=256){
    h4 z = {(_Float16)0.f,(_Float16)0.f,(_Float16)0.f,(_Float16)0.f};
    ((h4*)hn)[272+i] = z;
  }

  float ga=g2[lane], gb=g2[lane+64], ba=b2v[lane], bbx=b2v[lane+64];
#pragma unroll
  for (int rr=0;rr<2;++rr){
    int r = w + rr*4;
    size_t gi = (size_t)(n0+r)*DOUTC + lane;
    float a  = (float)xph[gi]    + ctxb[gi];
    float cc = (float)xph[gi+64] + ctxb[gi+64];
    hrow[r][lane] = a; hrow[r][lane+64] = cc;
    float s = wsum(a+cc);
    float q = wsum(a*a+cc*cc);
    float mean = s*(1.f/DOUTC);
    float var  = q*(1.f/DOUTC) - mean*mean;
    float rstd = rsqrtf(var + 1e-5f);
    hn[r][lane]    = (_Float16)((a -mean)*rstd*ga + ba);
    hn[r][lane+64] = (_Float16)((cc-mean)*rstd*gb + bbx);
  }
  __syncthreads();

  h4 hidB[4];
#pragma unroll
  for (int t=0;t<4;++t){
    int ht = 4*w + t;
    float4 bi = *(const float4*)(bb1 + 16*ht + 4*g);
    f32x4 D1; D1[0]=bi.x; D1[1]=bi.y; D1[2]=bi.z; D1[3]=bi.w;
#pragma unroll
    for (int kt=0;kt<8;++kt){
      h4 f;
#pragma unroll
      for (int j=0;j<4;++j)
        f[j] = (_Float16)W1[(size_t)(16*kt + 4*g + j)*256 + 16*ht + c];
      h4 hb = *(const h4*)&hn[c][16*kt + 4*g];
      D1 = __builtin_amdgcn_mfma_f32_16x16x16f16(f, hb, D1, 0,0,0);
    }
#pragma unroll
    for (int r=0;r<4;++r) hidB[t][r] = (_Float16)fmaxf(D1[r], 0.f);
  }

#pragma unroll
  for (int ot=0;ot<8;++ot){
    f32x4 d2 = {0.f,0.f,0.f,0.f};
#pragma unroll
    for (int t=0;t<4;++t){
      h4 f;
#pragma unroll
      for (int j=0;j<4;++j)
        f[j] = (_Float16)W2[(size_t)(16*(4*w+t) + 4*g + j)*128 + 16*ot + c];
      d2 = __builtin_amdgcn_mfma_f32_16x16x16f16(f, hidB[t], d2, 0,0,0);
    }
#pragma unroll
    for (int r=0;r<4;++r) part[w][ot][4*g+r][c] = d2[r];
  }
  __syncthreads();

#pragma unroll
  for (int i=tid;i<1024;i+=256){
    int n = i>>7, col = i&127;
    int ot = col>>4, m = col&15;
    float v = part[0][ot][m][n] + part[1][ot][m][n]
            + part[2][ot][m][n] + part[3][ot][m][n];
    out[(size_t)(n0+n)*DOUTC + col] = hrow[n][col] + v + bb2[col];
  }
}

extern "C" void kernel_launch(void* const* d_in, const int* in_sizes, int n_in,
                              void* d_out, int out_size, void* d_ws, size_t ws_size,
                              hipStream_t stream)
{
  const float* x     = (const float*)d_in[0];
  const int*   adj   = (const int*)  d_in[1];
  const float* ea    = (const float*)d_in[2];
  const float* ln1_g = (const float*)d_in[3];
  const float* ln1_b = (const float*)d_in[4];
  const float* Wp    = (const float*)d_in[5];
  const float* bp    = (const float*)d_in[6];
  const float* eln_g = (const float*)d_in[7];
  const float* eln_b = (const float*)d_in[8];
  const float* We1   = (const float*)d_in[9];
  const float* be1   = (const float*)d_in[10];
  const float* We2   = (const float*)d_in[11];
  const float* be2   = (const float*)d_in[12];
  const float* Wq    = (const float*)d_in[13];
  const float* Wk    = (const float*)d_in[14];
  const float* Wv    = (const float*)d_in[15];
  const float* ffW1  = (const float*)d_in[16];
  const float* ffb1  = (const float*)d_in[17];
  const float* ffW2  = (const float*)d_in[18];
  const float* ffb2  = (const float*)d_in[19];
  const float* ln2_g = (const float*)d_in[20];
  const float* ln2_b = (const float*)d_in[21];
  float* out = (float*)d_out;

  char* ws = (char*)d_ws;
  _Float16* xph = (_Float16*)(ws);                    // 1MB  (f16 now)
  float*    ctx = (float*)(ws + ((size_t)2<<20));     // 2MB
  _Float16* Qh  = (_Float16*)(ws + ((size_t)4<<20));  // 1MB
  _Float16* Kh  = (_Float16*)(ws + ((size_t)5<<20));  // 1MB
  _Float16* Vh  = (_Float16*)(ws + ((size_t)6<<20));  // 1MB
  _Float16* ebf = (_Float16*)(ws + ((size_t)7<<20));  // 32MB [B,H,N,N] f16 (mask baked)

  k_projedge<<<NPROJ + BB*NN, 256, 0, stream>>>(
      x, ln1_g, ln1_b, Wp, bp, Wq, Wk, Wv, xph, Qh, Kh, Vh,
      ea, adj, eln_g, eln_b, We1, be1, We2, be2, ebf);
  k_attn<<<BB*HHC*8, 256, 0, stream>>>(Qh, Kh, Vh, ebf, ctx);
  k_ffn<<<(BB*NN)/8, 256, 0, stream>>>(xph, ctx, ln2_g, ln2_b, ffW1, ffb1, ffW2, ffb2, out);
}

// Round 13
// 84.873 us; speedup vs baseline: 1.0513x; 1.0513x over previous
//
#include <hip/hip_runtime.h>
#include <hip/hip_bf16.h>

#define BB 8
#define NN 512
#define DINC 128
#define DOUTC 128
#define HHC 8
#define EEC 16
#define DHC 16
#define NEDGE (BB*NN)      // 4096 edge blocks first; proj blocks at the tail

typedef _Float16 h4 __attribute__((ext_vector_type(4)));
typedef float f32x4 __attribute__((ext_vector_type(4)));

__device__ __forceinline__ float wsum(float v){
#pragma unroll
  for (int o=1;o<64;o<<=1) v += __shfl_xor(v,o);
  return v;
}

// =================== merged edge ∥ proj kernel ===================
// Bodies are R11-verbatim (proven). Separate typed __shared__ arrays (no char*
// aliasing): edge 9.4KB + proj 21.8KB = ~31KB -> 5 blocks/CU (= R11's VGPR cap).
__global__ __launch_bounds__(256) void k_projedge(
    const float* __restrict__ x,
    const float* __restrict__ g1, const float* __restrict__ b1,
    const float* __restrict__ Wp, const float* __restrict__ bp,
    const float* __restrict__ Wq, const float* __restrict__ Wk, const float* __restrict__ Wv,
    _Float16* __restrict__ xph, _Float16* __restrict__ Qh, _Float16* __restrict__ Kh, _Float16* __restrict__ Vh,
    const float* __restrict__ ea, const int* __restrict__ adj,
    const float* __restrict__ eg, const float* __restrict__ ebi,
    const float* __restrict__ We1, const float* __restrict__ be1,
    const float* __restrict__ We2, const float* __restrict__ be2,
    _Float16* __restrict__ ebias)
{
  // ---- edge-path LDS (R10/R11 layout)
  __shared__ _Float16 stage[8][520];
  __shared__ unsigned long long msk[8];
  __shared__ unsigned short idx16[512];
  __shared__ int cntS;
  // ---- proj-path LDS (R11/R12 layout, f16 xp)
  __shared__ _Float16 xln[16][136];
  __shared__ _Float16 xps[16][136];
  __shared__ _Float16 qs[3][16][136];

  int tid = threadIdx.x, w = tid>>6, lane = tid&63;
  int c = lane&15, g = lane>>4;

  if (blockIdx.x < NEDGE){
    // ================= edge body (R10/R11-verified, verbatim) =================
    int bn = blockIdx.x;
    int b = bn >> 9, n = bn & (NN-1);

    const int* adjRow = adj + (size_t)bn*NN;
    int col1 = tid, col2 = tid + 256;
    int v1 = (adjRow[col1] != 0) || (col1 == n);
    int v2 = (adjRow[col2] != 0) || (col2 == n);
    unsigned long long b1m = __ballot(v1);
    unsigned long long b2m = __ballot(v2);
    if (lane==0){ msk[w] = b1m; msk[4+w] = b2m; }

    h4 w1a,w1b,w2a,w2b;
#pragma unroll
    for (int j=0;j<4;++j){
      w1a[j] = (_Float16)We1[(4*g+j)*32 + c];
      w1b[j] = (_Float16)We1[(4*g+j)*32 + 16 + c];
      w2a[j] = (_Float16)((c<8)? We2[(4*g+j)*HHC + c] : 0.f);
      w2b[j] = (_Float16)((c<8)? We2[(16+4*g+j)*HHC + c] : 0.f);
    }
    float4 b1a = *(const float4*)(be1 + 4*g);
    float4 b1b = *(const float4*)(be1 + 16 + 4*g);
    float4 b2r = *(const float4*)(be2 + (g&1)*4);
    float4 G4  = *(const float4*)(eg  + 4*g);
    float4 Bv4 = *(const float4*)(ebi + 4*g);

    __syncthreads();

    int offs[8]; int cnt = 0;
#pragma unroll
    for (int k=0;k<8;++k){ offs[k] = cnt; cnt += __popcll(msk[k]); }
    if (tid==0) cntS = cnt;

    {
      _Float16 neg = (_Float16)(-30000.f);
      h4 negv; negv[0]=neg; negv[1]=neg; negv[2]=neg; negv[3]=neg;
#pragma unroll
      for (int i=tid;i<1024;i+=256){
        int h = i>>7, m4 = i&127;
        *(h4*)&stage[h][m4*4] = negv;
      }
    }

    if (v1){
      int pos = offs[w]   + __popcll(msk[w]   & ((1ull<<lane)-1ull));
      idx16[pos] = (unsigned short)col1;
    }
    if (v2){
      int pos = offs[4+w] + __popcll(msk[4+w] & ((1ull<<lane)-1ull));
      idx16[pos] = (unsigned short)col2;
    }
    __syncthreads();

    cnt = cntS;
    int nt = (cnt + 15) >> 4;
    const float* eaRow = ea + (size_t)bn*NN*EEC;

    for (int t = w; t < nt; t += 4){
      int slot = 16*t + c;
      int sidx = slot < cnt ? slot : cnt-1;
      int idx  = idx16[sidx];
      float4 v = *(const float4*)(eaRow + (size_t)idx*EEC + 4*g);
      float s = v.x+v.y+v.z+v.w;
      float q = v.x*v.x+v.y*v.y+v.z*v.z+v.w*v.w;
      s += __shfl_xor(s,16); s += __shfl_xor(s,32);
      q += __shfl_xor(q,16); q += __shfl_xor(q,32);
      float mean = s*(1.f/EEC);
      float var  = q*(1.f/EEC) - mean*mean;
      float rstd = rsqrtf(var + 1e-5f);
      h4 ef;
      ef[0]=(_Float16)((v.x-mean)*rstd*G4.x + Bv4.x);
      ef[1]=(_Float16)((v.y-mean)*rstd*G4.y + Bv4.y);
      ef[2]=(_Float16)((v.z-mean)*rstd*G4.z + Bv4.z);
      ef[3]=(_Float16)((v.w-mean)*rstd*G4.w + Bv4.w);
      f32x4 d1a = {b1a.x,b1a.y,b1a.z,b1a.w};
      f32x4 d1b = {b1b.x,b1b.y,b1b.z,b1b.w};
      d1a = __builtin_amdgcn_mfma_f32_16x16x16f16(w1a, ef, d1a, 0,0,0);
      d1b = __builtin_amdgcn_mfma_f32_16x16x16f16(w1b, ef, d1b, 0,0,0);
      h4 hfa,hfb;
#pragma unroll
      for (int r=0;r<4;++r){
        hfa[r]=(_Float16)fmaxf(d1a[r],0.f);
        hfb[r]=(_Float16)fmaxf(d1b[r],0.f);
      }
      f32x4 d2 = {0.f,0.f,0.f,0.f};
      d2 = __builtin_amdgcn_mfma_f32_16x16x16f16(w2a, hfa, d2, 0,0,0);
      d2 = __builtin_amdgcn_mfma_f32_16x16x16f16(w2b, hfb, d2, 0,0,0);
      if (g<2 && slot<cnt){
#pragma unroll
        for (int r=0;r<4;++r){
          float y = d2[r] + ((const float*)&b2r)[r];
          y = fminf(fmaxf(2.f*y,-30.f),30.f);
          float ex = __expf(y);
          float t2 = (ex-1.f)/(ex+1.f);
          stage[4*g+r][idx] = (_Float16)(5.f*t2);
        }
      }
    }
    __syncthreads();

    size_t base = ((size_t)b*HHC)*NN*NN + (size_t)n*NN;
#pragma unroll
    for (int i=tid;i<512;i+=256){
      int h = i>>6, m8 = i&63;
      *(float4*)(ebias + base + (size_t)h*NN*NN + m8*8) =
          *(const float4*)&stage[h][m8*8];
    }
  } else {
    // ================= proj body (R11/R12-verified, verbatim) =================
    int blk = blockIdx.x - NEDGE;
    int row0 = blk*16;
    int b = row0>>9, n0 = row0&(NN-1);

    float ga=g1[lane], gb=g1[lane+64], ba=b1[lane], bbx=b1[lane+64];
#pragma unroll
    for (int rr=0;rr<4;++rr){
      int r = w + rr*4;
      size_t gi = (size_t)(row0+r)*DINC + lane;
      float a = x[gi], cc = x[gi+64];
      float s = wsum(a+cc);
      float q = wsum(a*a+cc*cc);
      float mean = s*(1.f/DINC);
      float var  = q*(1.f/DINC)-mean*mean;
      float rstd = rsqrtf(var+1e-5f);
      xln[r][lane]    = (_Float16)((a -mean)*rstd*ga + ba);
      xln[r][lane+64] = (_Float16)((cc-mean)*rstd*gb + bbx);
    }
    __syncthreads();

#pragma unroll
    for (int oo=0;oo<2;++oo){
      int ot = 2*w+oo;
      float4 bi = *(const float4*)(bp + 16*ot + 4*g);
      f32x4 D; D[0]=bi.x; D[1]=bi.y; D[2]=bi.z; D[3]=bi.w;
#pragma unroll
      for (int kt=0;kt<8;++kt){
        h4 f;
#pragma unroll
        for (int j=0;j<4;++j)
          f[j] = (_Float16)Wp[(size_t)(16*kt+4*g+j)*DOUTC + 16*ot + c];
        h4 hb = *(const h4*)&xln[c][16*kt+4*g];
        D = __builtin_amdgcn_mfma_f32_16x16x16f16(f, hb, D, 0,0,0);
      }
#pragma unroll
      for (int r=0;r<4;++r)
        xps[c][16*ot+4*g+r] = (_Float16)D[r];
    }
    __syncthreads();

#pragma unroll
    for (int pp=0;pp<6;++pp){
      int p = w + pp*4;
      int mat = p>>3, ot = p&7;
      const float* W = (mat==0)? Wq : ((mat==1)? Wk : Wv);
      f32x4 D = {0.f,0.f,0.f,0.f};
#pragma unroll
      for (int kt=0;kt<8;++kt){
        h4 f;
#pragma unroll
        for (int j=0;j<4;++j)
          f[j] = (_Float16)W[(size_t)(16*kt+4*g+j)*DOUTC + 16*ot + c];
        h4 hb = *(const h4*)&xps[c][16*kt+4*g];
        D = __builtin_amdgcn_mfma_f32_16x16x16f16(f, hb, D, 0,0,0);
      }
#pragma unroll
      for (int r=0;r<4;++r)
        qs[mat][c][16*ot+4*g+r] = (_Float16)D[r];
    }
    __syncthreads();

    { // xp (f16) writeout
      int r = tid>>4, seg = tid&15;
      *(float4*)(xph + (size_t)(row0+r)*DOUTC + seg*8) = *(const float4*)&xps[r][seg*8];
    }
#pragma unroll
    for (int mat=0;mat<3;++mat){
      int r = tid>>4, seg = tid&15;
      int h = seg>>1, d = (seg&1)*8;
      _Float16* O = (mat==0)? Qh : ((mat==1)? Kh : Vh);
      *(float4*)(O + (((size_t)b*HHC+h)*NN + n0+r)*DHC + d) = *(const float4*)&qs[mat][r][seg*8];
    }
  }
}

// ---------- MFMA attention (R9-R12-verified, unchanged) ----------
__global__ __launch_bounds__(256) void k_attn(
  const _Float16* __restrict__ Qh, const _Float16* __restrict__ Kh, const _Float16* __restrict__ Vh,
  const _Float16* __restrict__ eb, float* __restrict__ ctxb)
{
  __shared__ _Float16 Klds[NN*DHC];
  __shared__ _Float16 Vt[DHC*520];
  int tid = threadIdx.x;
  int bh   = blockIdx.x >> 3;
  int tile = blockIdx.x & 7;
  const _Float16* Kg = Kh + (size_t)bh*NN*DHC;
  const _Float16* Vg = Vh + (size_t)bh*NN*DHC;
  {
    const float4* src = (const float4*)Kg;
    float4* dst = (float4*)Klds;
#pragma unroll
    for (int i=tid;i<1024;i+=256) dst[i]=src[i];
  }
  {
#pragma unroll
    for (int i=tid;i<1024;i+=256){
      int m = i>>1, hf = i&1;
      float4 v4 = *(const float4*)(Vg + (size_t)m*DHC + hf*8);
      const _Float16* hh = (const _Float16*)&v4;
#pragma unroll
      for (int jj=0;jj<8;++jj) Vt[(hf*8+jj)*520 + m] = hh[jj];
    }
  }
  __syncthreads();

  int w = tid>>6, lane = tid&63;
  int c = lane&15, g = lane>>4;
  int n0 = tile*64 + w*16;

  h4 qf = *(const h4*)(Qh + ((size_t)bh*NN + n0 + c)*DHC + 4*g);
  const _Float16* ebw = eb + ((size_t)bh*NN + n0 + c)*NN + 4*g;

  f32x4 zero = {0.f,0.f,0.f,0.f};
  f32x4 acc = zero;
  float rowsum = 0.f;
#pragma unroll
  for (int t=0;t<32;++t){
    h4 kf = *(const h4*)(Klds + (16*t + c)*DHC + 4*g);
    f32x4 d = __builtin_amdgcn_mfma_f32_16x16x16f16(kf, qf, zero, 0, 0, 0);
    h4 e4 = *(const h4*)(ebw + 16*t);
    h4 pa;
#pragma unroll
    for (int r=0;r<4;++r){
      float sv = d[r]*0.25f + (float)e4[r];
      sv = fmaxf(sv,0.f) + 0.2f*fminf(sv,0.f);
      float p = __expf(sv - 6.f);
      rowsum += p;
      pa[r] = (_Float16)p;
    }
    h4 vf = *(const h4*)(Vt + c*520 + 16*t + 4*g);
    acc = __builtin_amdgcn_mfma_f32_16x16x16f16(pa, vf, acc, 0, 0, 0);
  }
  rowsum += __shfl_xor(rowsum,16);
  rowsum += __shfl_xor(rowsum,32);

  int b = bh>>3, h = bh&7;
#pragma unroll
  for (int r=0;r<4;++r){
    float sr = __shfl(rowsum, g*16 + 4*g + r);
    ctxb[((size_t)b*NN + n0 + 4*g + r)*DOUTC + h*DHC + c] = acc[r]/sr;
  }
}

// ---------- FFN v4 (R12-verified, xp f16, unchanged) ----------
__global__ __launch_bounds__(256) void k_ffn(
  const _Float16* __restrict__ xph, const float* __restrict__ ctxb,
  const float* __restrict__ g2, const float* __restrict__ b2v,
  const float* __restrict__ W1, const float* __restrict__ bb1,
  const float* __restrict__ W2, const float* __restrict__ bb2,
  float* __restrict__ out)
{
  __shared__ float    hrow[8][DOUTC];
  __shared__ _Float16 hn[16][136];
  __shared__ float    part[4][8][16][16];

  int tid = threadIdx.x, w = tid>>6, lane = tid&63;
  int c = lane&15, g = lane>>4;
  int n0 = blockIdx.x * 8;

#pragma unroll
  for (int i=tid;i<272;i+=256){
    h4 z = {(_Float16)0.f,(_Float16)0.f,(_Float16)0.f,(_Float16)0.f};
    ((h4*)hn)[272+i] = z;
  }

  float ga=g2[lane], gb=g2[lane+64], ba=b2v[lane], bbx=b2v[lane+64];
#pragma unroll
  for (int rr=0;rr<2;++rr){
    int r = w + rr*4;
    size_t gi = (size_t)(n0+r)*DOUTC + lane;
    float a  = (float)xph[gi]    + ctxb[gi];
    float cc = (float)xph[gi+64] + ctxb[gi+64];
    hrow[r][lane] = a; hrow[r][lane+64] = cc;
    float s = wsum(a+cc);
    float q = wsum(a*a+cc*cc);
    float mean = s*(1.f/DOUTC);
    float var  = q*(1.f/DOUTC) - mean*mean;
    float rstd = rsqrtf(var + 1e-5f);
    hn[r][lane]    = (_Float16)((a -mean)*rstd*ga + ba);
    hn[r][lane+64] = (_Float16)((cc-mean)*rstd*gb + bbx);
  }
  __syncthreads();

  h4 hidB[4];
#pragma unroll
  for (int t=0;t<4;++t){
    int ht = 4*w + t;
    float4 bi = *(const float4*)(bb1 + 16*ht + 4*g);
    f32x4 D1; D1[0]=bi.x; D1[1]=bi.y; D1[2]=bi.z; D1[3]=bi.w;
#pragma unroll
    for (int kt=0;kt<8;++kt){
      h4 f;
#pragma unroll
      for (int j=0;j<4;++j)
        f[j] = (_Float16)W1[(size_t)(16*kt + 4*g + j)*256 + 16*ht + c];
      h4 hb = *(const h4*)&hn[c][16*kt + 4*g];
      D1 = __builtin_amdgcn_mfma_f32_16x16x16f16(f, hb, D1, 0,0,0);
    }
#pragma unroll
    for (int r=0;r<4;++r) hidB[t][r] = (_Float16)fmaxf(D1[r], 0.f);
  }

#pragma unroll
  for (int ot=0;ot<8;++ot){
    f32x4 d2 = {0.f,0.f,0.f,0.f};
#pragma unroll
    for (int t=0;t<4;++t){
      h4 f;
#pragma unroll
      for (int j=0;j<4;++j)
        f[j] = (_Float16)W2[(size_t)(16*(4*w+t) + 4*g + j)*128 + 16*ot + c];
      d2 = __builtin_amdgcn_mfma_f32_16x16x16f16(f, hidB[t], d2, 0,0,0);
    }
#pragma unroll
    for (int r=0;r<4;++r) part[w][ot][4*g+r][c] = d2[r];
  }
  __syncthreads();

#pragma unroll
  for (int i=tid;i<1024;i+=256){
    int n = i>>7, col = i&127;
    int ot = col>>4, m = col&15;
    float v = part[0][ot][m][n] + part[1][ot][m][n]
            + part[2][ot][m][n] + part[3][ot][m][n];
    out[(size_t)(n0+n)*DOUTC + col] = hrow[n][col] + v + bb2[col];
  }
}

extern "C" void kernel_launch(void* const* d_in, const int* in_sizes, int n_in,
                              void* d_out, int out_size, void* d_ws, size_t ws_size,
                              hipStream_t stream)
{
  const float* x     = (const float*)d_in[0];
  const int*   adj   = (const int*)  d_in[1];
  const float* ea    = (const float*)d_in[2];
  const float* ln1_g = (const float*)d_in[3];
  const float* ln1_b = (const float*)d_in[4];
  const float* Wp    = (const float*)d_in[5];
  const float* bp    = (const float*)d_in[6];
  const float* eln_g = (const float*)d_in[7];
  const float* eln_b = (const float*)d_in[8];
  const float* We1   = (const float*)d_in[9];
  const float* be1   = (const float*)d_in[10];
  const float* We2   = (const float*)d_in[11];
  const float* be2   = (const float*)d_in[12];
  const float* Wq    = (const float*)d_in[13];
  const float* Wk    = (const float*)d_in[14];
  const float* Wv    = (const float*)d_in[15];
  const float* ffW1  = (const float*)d_in[16];
  const float* ffb1  = (const float*)d_in[17];
  const float* ffW2  = (const float*)d_in[18];
  const float* ffb2  = (const float*)d_in[19];
  const float* ln2_g = (const float*)d_in[20];
  const float* ln2_b = (const float*)d_in[21];
  float* out = (float*)d_out;

  char* ws = (char*)d_ws;
  _Float16* xph = (_Float16*)(ws);                    // 0.5MB (f16)
  float*    ctx = (float*)(ws + ((size_t)2<<20));     // 2MB
  _Float16* Qh  = (_Float16*)(ws + ((size_t)4<<20));  // 1MB
  _Float16* Kh  = (_Float16*)(ws + ((size_t)5<<20));  // 1MB
  _Float16* Vh  = (_Float16*)(ws + ((size_t)6<<20));  // 1MB
  _Float16* ebf = (_Float16*)(ws + ((size_t)7<<20));  // 32MB [B,H,N,N] f16 (mask baked)

  k_projedge<<<NEDGE + (BB*NN)/16, 256, 0, stream>>>(
      x, ln1_g, ln1_b, Wp, bp, Wq, Wk, Wv, xph, Qh, Kh, Vh,
      ea, adj, eln_g, eln_b, We1, be1, We2, be2, ebf);
  k_attn<<<BB*HHC*8, 256, 0, stream>>>(Qh, Kh, Vh, ebf, ctx);
  k_ffn<<<(BB*NN)/8, 256, 0, stream>>>(xph, ctx, ln2_g, ln2_b, ffW1, ffb1, ffW2, ffb2, out);
}

// Round 14
// 82.368 us; speedup vs baseline: 1.0833x; 1.0304x over previous
//
#include <hip/hip_runtime.h>
#include <hip/hip_bf16.h>

#define BB 8
#define NN 512
#define DINC 128
#define DOUTC 128
#define HHC 8
#define EEC 16
#define DHC 16

typedef _Float16 h4 __attribute__((ext_vector_type(4)));
typedef float f32x4 __attribute__((ext_vector_type(4)));

__device__ __forceinline__ float wsum(float v){
#pragma unroll
  for (int o=1;o<64;o<<=1) v += __shfl_xor(v,o);
  return v;
}

// ---------- proj v2 (R11-verified): LN1 + MFMA GEMMs ----------
__global__ __launch_bounds__(256) void k_proj(
    const float* __restrict__ x,
    const float* __restrict__ g1, const float* __restrict__ b1,
    const float* __restrict__ Wp, const float* __restrict__ bp,
    const float* __restrict__ Wq, const float* __restrict__ Wk, const float* __restrict__ Wv,
    float* __restrict__ xp, _Float16* __restrict__ Qh, _Float16* __restrict__ Kh, _Float16* __restrict__ Vh)
{
  __shared__ _Float16 xln[16][136];
  __shared__ _Float16 xps[16][136];
  __shared__ float    xp32[16][132];
  __shared__ _Float16 qs[3][16][136];
  int tid=threadIdx.x, w=tid>>6, lane=tid&63;
  int c=lane&15, g=lane>>4;
  int row0 = blockIdx.x*16;
  int b = row0>>9, n0 = row0&(NN-1);

  float ga=g1[lane], gb=g1[lane+64], ba=b1[lane], bbx=b1[lane+64];
#pragma unroll
  for (int rr=0;rr<4;++rr){
    int r = w + rr*4;
    size_t gi = (size_t)(row0+r)*DINC + lane;
    float a = x[gi], cc = x[gi+64];
    float s = wsum(a+cc);
    float q = wsum(a*a+cc*cc);
    float mean = s*(1.f/DINC);
    float var  = q*(1.f/DINC)-mean*mean;
    float rstd = rsqrtf(var+1e-5f);
    xln[r][lane]    = (_Float16)((a -mean)*rstd*ga + ba);
    xln[r][lane+64] = (_Float16)((cc-mean)*rstd*gb + bbx);
  }
  __syncthreads();

#pragma unroll
  for (int oo=0;oo<2;++oo){
    int ot = 2*w+oo;
    float4 bi = *(const float4*)(bp + 16*ot + 4*g);
    f32x4 D; D[0]=bi.x; D[1]=bi.y; D[2]=bi.z; D[3]=bi.w;
#pragma unroll
    for (int kt=0;kt<8;++kt){
      h4 f;
#pragma unroll
      for (int j=0;j<4;++j)
        f[j] = (_Float16)Wp[(size_t)(16*kt+4*g+j)*DOUTC + 16*ot + c];
      h4 hb = *(const h4*)&xln[c][16*kt+4*g];
      D = __builtin_amdgcn_mfma_f32_16x16x16f16(f, hb, D, 0,0,0);
    }
#pragma unroll
    for (int r=0;r<4;++r){
      xp32[c][16*ot+4*g+r] = D[r];
      xps [c][16*ot+4*g+r] = (_Float16)D[r];
    }
  }
  __syncthreads();

#pragma unroll
  for (int pp=0;pp<6;++pp){
    int p = w + pp*4;
    int mat = p>>3, ot = p&7;
    const float* W = (mat==0)? Wq : ((mat==1)? Wk : Wv);
    f32x4 D = {0.f,0.f,0.f,0.f};
#pragma unroll
    for (int kt=0;kt<8;++kt){
      h4 f;
#pragma unroll
      for (int j=0;j<4;++j)
        f[j] = (_Float16)W[(size_t)(16*kt+4*g+j)*DOUTC + 16*ot + c];
      h4 hb = *(const h4*)&xps[c][16*kt+4*g];
      D = __builtin_amdgcn_mfma_f32_16x16x16f16(f, hb, D, 0,0,0);
    }
#pragma unroll
    for (int r=0;r<4;++r)
      qs[mat][c][16*ot+4*g+r] = (_Float16)D[r];
  }
  __syncthreads();

#pragma unroll
  for (int i=tid;i<512;i+=256){
    int r=i>>5, seg=i&31;
    *(float4*)(xp + (size_t)(row0+r)*DOUTC + seg*4) = *(const float4*)&xp32[r][seg*4];
  }
#pragma unroll
  for (int mat=0;mat<3;++mat){
    int r = tid>>4, seg = tid&15;
    int h = seg>>1, d = (seg&1)*8;
    _Float16* O = (mat==0)? Qh : ((mat==1)? Kh : Vh);
    *(float4*)(O + (((size_t)b*HHC+h)*NN + n0+r)*DHC + d) = *(const float4*)&qs[mat][r][seg*8];
  }
}

// ---------- edge-bias MLP v5: R10/R11 compaction + depth-1 gather prefetch ----------
// Each wave always has the NEXT tile's 16B gather in flight under the current
// tile's ~800cy LN->MFMA->tanh chain (counters: gather latency-bound at 1.1TB/s).
__global__ __launch_bounds__(256) void k_edge(
  const float* __restrict__ ea, const int* __restrict__ adj,
  const float* __restrict__ eg, const float* __restrict__ ebi,
  const float* __restrict__ We1, const float* __restrict__ be1,
  const float* __restrict__ We2, const float* __restrict__ be2,
  _Float16* __restrict__ ebias)
{
  __shared__ _Float16 stage[8][520];
  __shared__ unsigned long long msk[8];
  __shared__ unsigned short idx16[512];
  __shared__ int cntS;

  int tid = threadIdx.x, w = tid>>6, lane = tid&63;
  int c = lane&15, g = lane>>4;
  int bn = blockIdx.x;
  int b = bn >> 9, n = bn & (NN-1);

  const int* adjRow = adj + (size_t)bn*NN;
  int col1 = tid, col2 = tid + 256;
  int v1 = (adjRow[col1] != 0) || (col1 == n);
  int v2 = (adjRow[col2] != 0) || (col2 == n);
  unsigned long long b1m = __ballot(v1);
  unsigned long long b2m = __ballot(v2);
  if (lane==0){ msk[w] = b1m; msk[4+w] = b2m; }

  h4 w1a,w1b,w2a,w2b;
#pragma unroll
  for (int j=0;j<4;++j){
    w1a[j] = (_Float16)We1[(4*g+j)*32 + c];
    w1b[j] = (_Float16)We1[(4*g+j)*32 + 16 + c];
    w2a[j] = (_Float16)((c<8)? We2[(4*g+j)*HHC + c] : 0.f);
    w2b[j] = (_Float16)((c<8)? We2[(16+4*g+j)*HHC + c] : 0.f);
  }
  float4 b1a = *(const float4*)(be1 + 4*g);
  float4 b1b = *(const float4*)(be1 + 16 + 4*g);
  float4 b2r = *(const float4*)(be2 + (g&1)*4);
  float4 G4  = *(const float4*)(eg  + 4*g);
  float4 Bv4 = *(const float4*)(ebi + 4*g);

  __syncthreads();

  int offs[8]; int cnt = 0;
#pragma unroll
  for (int k=0;k<8;++k){ offs[k] = cnt; cnt += __popcll(msk[k]); }
  if (tid==0) cntS = cnt;

  {
    _Float16 neg = (_Float16)(-30000.f);
    h4 negv; negv[0]=neg; negv[1]=neg; negv[2]=neg; negv[3]=neg;
#pragma unroll
    for (int i=tid;i<1024;i+=256){
      int h = i>>7, m4 = i&127;
      *(h4*)&stage[h][m4*4] = negv;
    }
  }

  if (v1){
    int pos = offs[w]   + __popcll(msk[w]   & ((1ull<<lane)-1ull));
    idx16[pos] = (unsigned short)col1;
  }
  if (v2){
    int pos = offs[4+w] + __popcll(msk[4+w] & ((1ull<<lane)-1ull));
    idx16[pos] = (unsigned short)col2;
  }
  __syncthreads();

  cnt = cntS;
  int nt = (cnt + 15) >> 4;
  const float* eaRow = ea + (size_t)bn*NN*EEC;

  // ---- prologue: prefetch first tile
  int idxCur = 0;
  float4 vCur = {0.f,0.f,0.f,0.f};
  if (w < nt){
    int slot0 = 16*w + c;
    int sidx0 = slot0 < cnt ? slot0 : cnt-1;
    idxCur = idx16[sidx0];
    vCur = *(const float4*)(eaRow + (size_t)idxCur*EEC + 4*g);
  }

  for (int t = w; t < nt; t += 4){
    // ---- issue NEXT tile's gather (rides under this tile's MLP chain)
    int idxNxt = 0;
    float4 vNxt = {0.f,0.f,0.f,0.f};
    if (t + 4 < nt){
      int slotn = 16*(t+4) + c;
      int sidxn = slotn < cnt ? slotn : cnt-1;
      idxNxt = idx16[sidxn];
      vNxt = *(const float4*)(eaRow + (size_t)idxNxt*EEC + 4*g);
    }
    // ---- process current tile (R10/R11-verified math, verbatim)
    int slot = 16*t + c;
    int idx  = idxCur;
    float4 v = vCur;
    float s = v.x+v.y+v.z+v.w;
    float q = v.x*v.x+v.y*v.y+v.z*v.z+v.w*v.w;
    s += __shfl_xor(s,16); s += __shfl_xor(s,32);
    q += __shfl_xor(q,16); q += __shfl_xor(q,32);
    float mean = s*(1.f/EEC);
    float var  = q*(1.f/EEC) - mean*mean;
    float rstd = rsqrtf(var + 1e-5f);
    h4 ef;
    ef[0]=(_Float16)((v.x-mean)*rstd*G4.x + Bv4.x);
    ef[1]=(_Float16)((v.y-mean)*rstd*G4.y + Bv4.y);
    ef[2]=(_Float16)((v.z-mean)*rstd*G4.z + Bv4.z);
    ef[3]=(_Float16)((v.w-mean)*rstd*G4.w + Bv4.w);
    f32x4 d1a = {b1a.x,b1a.y,b1a.z,b1a.w};
    f32x4 d1b = {b1b.x,b1b.y,b1b.z,b1b.w};
    d1a = __builtin_amdgcn_mfma_f32_16x16x16f16(w1a, ef, d1a, 0,0,0);
    d1b = __builtin_amdgcn_mfma_f32_16x16x16f16(w1b, ef, d1b, 0,0,0);
    h4 hfa,hfb;
#pragma unroll
    for (int r=0;r<4;++r){
      hfa[r]=(_Float16)fmaxf(d1a[r],0.f);
      hfb[r]=(_Float16)fmaxf(d1b[r],0.f);
    }
    f32x4 d2 = {0.f,0.f,0.f,0.f};
    d2 = __builtin_amdgcn_mfma_f32_16x16x16f16(w2a, hfa, d2, 0,0,0);
    d2 = __builtin_amdgcn_mfma_f32_16x16x16f16(w2b, hfb, d2, 0,0,0);
    if (g<2 && slot<cnt){
#pragma unroll
      for (int r=0;r<4;++r){
        float y = d2[r] + ((const float*)&b2r)[r];
        y = fminf(fmaxf(2.f*y,-30.f),30.f);
        float ex = __expf(y);
        float t2 = (ex-1.f)/(ex+1.f);
        stage[4*g+r][idx] = (_Float16)(5.f*t2);
      }
    }
    // ---- rotate double-buffer (static names, no runtime indexing)
    idxCur = idxNxt;
    vCur = vNxt;
  }
  __syncthreads();

  size_t base = ((size_t)b*HHC)*NN*NN + (size_t)n*NN;
#pragma unroll
  for (int i=tid;i<512;i+=256){
    int h = i>>6, m8 = i&63;
    *(float4*)(ebias + base + (size_t)h*NN*NN + m8*8) =
        *(const float4*)&stage[h][m8*8];
  }
}

// ---------- MFMA attention (R9-R13-verified, unchanged) ----------
__global__ __launch_bounds__(256) void k_attn(
  const _Float16* __restrict__ Qh, const _Float16* __restrict__ Kh, const _Float16* __restrict__ Vh,
  const _Float16* __restrict__ eb, float* __restrict__ ctxb)
{
  __shared__ _Float16 Klds[NN*DHC];
  __shared__ _Float16 Vt[DHC*520];
  int tid = threadIdx.x;
  int bh   = blockIdx.x >> 3;
  int tile = blockIdx.x & 7;
  const _Float16* Kg = Kh + (size_t)bh*NN*DHC;
  const _Float16* Vg = Vh + (size_t)bh*NN*DHC;
  {
    const float4* src = (const float4*)Kg;
    float4* dst = (float4*)Klds;
#pragma unroll
    for (int i=tid;i<1024;i+=256) dst[i]=src[i];
  }
  {
#pragma unroll
    for (int i=tid;i<1024;i+=256){
      int m = i>>1, hf = i&1;
      float4 v4 = *(const float4*)(Vg + (size_t)m*DHC + hf*8);
      const _Float16* hh = (const _Float16*)&v4;
#pragma unroll
      for (int jj=0;jj<8;++jj) Vt[(hf*8+jj)*520 + m] = hh[jj];
    }
  }
  __syncthreads();

  int w = tid>>6, lane = tid&63;
  int c = lane&15, g = lane>>4;
  int n0 = tile*64 + w*16;

  h4 qf = *(const h4*)(Qh + ((size_t)bh*NN + n0 + c)*DHC + 4*g);
  const _Float16* ebw = eb + ((size_t)bh*NN + n0 + c)*NN + 4*g;

  f32x4 zero = {0.f,0.f,0.f,0.f};
  f32x4 acc = zero;
  float rowsum = 0.f;
#pragma unroll
  for (int t=0;t<32;++t){
    h4 kf = *(const h4*)(Klds + (16*t + c)*DHC + 4*g);
    f32x4 d = __builtin_amdgcn_mfma_f32_16x16x16f16(kf, qf, zero, 0, 0, 0);
    h4 e4 = *(const h4*)(ebw + 16*t);
    h4 pa;
#pragma unroll
    for (int r=0;r<4;++r){
      float sv = d[r]*0.25f + (float)e4[r];
      sv = fmaxf(sv,0.f) + 0.2f*fminf(sv,0.f);
      float p = __expf(sv - 6.f);
      rowsum += p;
      pa[r] = (_Float16)p;
    }
    h4 vf = *(const h4*)(Vt + c*520 + 16*t + 4*g);
    acc = __builtin_amdgcn_mfma_f32_16x16x16f16(pa, vf, acc, 0, 0, 0);
  }
  rowsum += __shfl_xor(rowsum,16);
  rowsum += __shfl_xor(rowsum,32);

  int b = bh>>3, h = bh&7;
#pragma unroll
  for (int r=0;r<4;++r){
    float sr = __shfl(rowsum, g*16 + 4*g + r);
    ctxb[((size_t)b*NN + n0 + 4*g + r)*DOUTC + h*DHC + c] = acc[r]/sr;
  }
}

// ---------- FFN v4 (R11-verified, f32 xp, unchanged) ----------
__global__ __launch_bounds__(256) void k_ffn(
  const float* __restrict__ xp, const float* __restrict__ ctxb,
  const float* __restrict__ g2, const float* __restrict__ b2v,
  const float* __restrict__ W1, const float* __restrict__ bb1,
  const float* __restrict__ W2, const float* __restrict__ bb2,
  float* __restrict__ out)
{
  __shared__ float    hrow[8][DOUTC];
  __shared__ _Float16 hn[16][136];
  __shared__ float    part[4][8][16][16];

  int tid = threadIdx.x, w = tid>>6, lane = tid&63;
  int c = lane&15, g = lane>>4;
  int n0 = blockIdx.x * 8;

#pragma unroll
  for (int i=tid;i<272;i+=256){
    h4 z = {(_Float16)0.f,(_Float16)0.f,(_Float16)0.f,(_Float16)0.f};
    ((h4*)hn)[272+i] = z;
  }

  float ga=g2[lane], gb=g2[lane+64], ba=b2v[lane], bbx=b2v[lane+64];
#pragma unroll
  for (int rr=0;rr<2;++rr){
    int r = w + rr*4;
    size_t gi = (size_t)(n0+r)*DOUTC + lane;
    float a  = xp[gi]    + ctxb[gi];
    float cc = xp[gi+64] + ctxb[gi+64];
    hrow[r][lane] = a; hrow[r][lane+64] = cc;
    float s = wsum(a+cc);
    float q = wsum(a*a+cc*cc);
    float mean = s*(1.f/DOUTC);
    float var  = q*(1.f/DOUTC) - mean*mean;
    float rstd = rsqrtf(var + 1e-5f);
    hn[r][lane]    = (_Float16)((a -mean)*rstd*ga + ba);
    hn[r][lane+64] = (_Float16)((cc-mean)*rstd*gb + bbx);
  }
  __syncthreads();

  h4 hidB[4];
#pragma unroll
  for (int t=0;t<4;++t){
    int ht = 4*w + t;
    float4 bi = *(const float4*)(bb1 + 16*ht + 4*g);
    f32x4 D1; D1[0]=bi.x; D1[1]=bi.y; D1[2]=bi.z; D1[3]=bi.w;
#pragma unroll
    for (int kt=0;kt<8;++kt){
      h4 f;
#pragma unroll
      for (int j=0;j<4;++j)
        f[j] = (_Float16)W1[(size_t)(16*kt + 4*g + j)*256 + 16*ht + c];
      h4 hb = *(const h4*)&hn[c][16*kt + 4*g];
      D1 = __builtin_amdgcn_mfma_f32_16x16x16f16(f, hb, D1, 0,0,0);
    }
#pragma unroll
    for (int r=0;r<4;++r) hidB[t][r] = (_Float16)fmaxf(D1[r], 0.f);
  }

#pragma unroll
  for (int ot=0;ot<8;++ot){
    f32x4 d2 = {0.f,0.f,0.f,0.f};
#pragma unroll
    for (int t=0;t<4;++t){
      h4 f;
#pragma unroll
      for (int j=0;j<4;++j)
        f[j] = (_Float16)W2[(size_t)(16*(4*w+t) + 4*g + j)*128 + 16*ot + c];
      d2 = __builtin_amdgcn_mfma_f32_16x16x16f16(f, hidB[t], d2, 0,0,0);
    }
#pragma unroll
    for (int r=0;r<4;++r) part[w][ot][4*g+r][c] = d2[r];
  }
  __syncthreads();

#pragma unroll
  for (int i=tid;i<1024;i+=256){
    int n = i>>7, col = i&127;
    int ot = col>>4, m = col&15;
    float v = part[0][ot][m][n] + part[1][ot][m][n]
            + part[2][ot][m][n] + part[3][ot][m][n];
    out[(size_t)(n0+n)*DOUTC + col] = hrow[n][col] + v + bb2[col];
  }
}

extern "C" void kernel_launch(void* const* d_in, const int* in_sizes, int n_in,
                              void* d_out, int out_size, void* d_ws, size_t ws_size,
                              hipStream_t stream)
{
  const float* x     = (const float*)d_in[0];
  const int*   adj   = (const int*)  d_in[1];
  const float* ea    = (const float*)d_in[2];
  const float* ln1_g = (const float*)d_in[3];
  const float* ln1_b = (const float*)d_in[4];
  const float* Wp    = (const float*)d_in[5];
  const float* bp    = (const float*)d_in[6];
  const float* eln_g = (const float*)d_in[7];
  const float* eln_b = (const float*)d_in[8];
  const float* We1   = (const float*)d_in[9];
  const float* be1   = (const float*)d_in[10];
  const float* We2   = (const float*)d_in[11];
  const float* be2   = (const float*)d_in[12];
  const float* Wq    = (const float*)d_in[13];
  const float* Wk    = (const float*)d_in[14];
  const float* Wv    = (const float*)d_in[15];
  const float* ffW1  = (const float*)d_in[16];
  const float* ffb1  = (const float*)d_in[17];
  const float* ffW2  = (const float*)d_in[18];
  const float* ffb2  = (const float*)d_in[19];
  const float* ln2_g = (const float*)d_in[20];
  const float* ln2_b = (const float*)d_in[21];
  float* out = (float*)d_out;

  char* ws = (char*)d_ws;
  float*    xp  = (float*)(ws);                       // 2MB (f32)
  float*    ctx = (float*)(ws + ((size_t)2<<20));     // 2MB
  _Float16* Qh  = (_Float16*)(ws + ((size_t)4<<20));  // 1MB
  _Float16* Kh  = (_Float16*)(ws + ((size_t)5<<20));  // 1MB
  _Float16* Vh  = (_Float16*)(ws + ((size_t)6<<20));  // 1MB
  _Float16* ebf = (_Float16*)(ws + ((size_t)7<<20));  // 32MB [B,H,N,N] f16 (mask baked)

  k_proj<<<(BB*NN)/16, 256, 0, stream>>>(x, ln1_g, ln1_b, Wp, bp, Wq, Wk, Wv, xp, Qh, Kh, Vh);
  k_edge<<<BB*NN, 256, 0, stream>>>(ea, adj, eln_g, eln_b, We1, be1, We2, be2, ebf);
  k_attn<<<BB*HHC*8, 256, 0, stream>>>(Qh, Kh, Vh, ebf, ctx);
  k_ffn<<<(BB*NN)/8, 256, 0, stream>>>(xp, ctx, ln2_g, ln2_b, ffW1, ffb1, ffW2, ffb2, out);
}